// Round 11
// baseline (287.113 us; speedup 1.0000x reference)
//
#include <hip/hip_runtime.h>

#define NNODES 100000
#define NEDGES 1250000
#define IN_CH 128
#define HID 64
#define BN_EPS 1e-5f

#define NPAD 100352               // NNODES rounded to 256 multiple
#define BIN_N 256                 // radix bins (391 nodes, 50 KB ELL slice)
#define BINW 391                  // ceil(NNODES / BIN_N); 256*391 = 100096
#define BIN_CHUNK 1024            // edges per block in pass-1 binning
#define BIN_BLOCKS 1221           // ceil(NEDGES / BIN_CHUNK)
#define BIN_CAP_LDS 16            // per-block per-bin LDS cap (mean 4)
#define BIN_REGION 10000          // per-bin staged cap (mean 4883, 2x)
#define MM_BLOCKS 1563            // (NNODES+63)/64 MFMA matmul tiles
#define GBLOCKS 3125              // gather blocks: 32 rows each (4 waves x 8)
#define ELL_C 32                  // ELL bucket capacity (128 B = d<<7 bytes)
#define OVF_CAP 65536             // overflow list capacity (robustness only)

typedef __attribute__((ext_vector_type(8))) short s16x8;   // 8 bf16 (4 VGPRs)
typedef __attribute__((ext_vector_type(4))) float f32x4;

__device__ __forceinline__ ushort f2bf(float f) {
    union { float f; unsigned int i; } c;
    c.f = f;
    unsigned int lsb = (c.i >> 16) & 1u;
    return (ushort)((c.i + 0x7FFFu + lsb) >> 16);   // round-to-nearest-even
}
__device__ __forceinline__ float asf(unsigned int i) {
    union { unsigned int i; float f; } c;
    c.i = i;
    return c.f;
}

// ELL insert; slot[d] ends at FULL degree of d (increments past ELL_C),
// so slot doubles as the degree array after the fill phase.
__device__ __forceinline__ void ell_insert(int d, int soff, int* slot,
                                           int* ell, int* ovf_n, int2* ovf) {
    int s = atomicAdd(&slot[d], 1);
    if (s < ELL_C) ell[(d << 5) + s] = soff;
    else {
        int oi = atomicAdd(ovf_n, 1);
        if (oi < OVF_CAP) ovf[oi] = make_int2(d, soff);
    }
}

// ---------------- fc matmul body (MFMA, 16 nodes x 64 cols per wave) ------
__device__ __forceinline__ void fc_body(
        int blk, int tid,
        const float* __restrict__ x, const float* __restrict__ w,
        const float* __restrict__ bb,
        const float* __restrict__ g, const float* __restrict__ be,
        const float* __restrict__ mu, const float* __restrict__ var,
        ushort* __restrict__ h0) {
    const int wave = tid >> 6;
    const int lane = tid & 63;
    const int m = lane & 15;
    const int q = lane >> 4;
    const int node_base = (blk * 4 + wave) * 16;

    s16x8 bfrag[4][4];
#pragma unroll
    for (int kc = 0; kc < 4; ++kc)
#pragma unroll
        for (int ct = 0; ct < 4; ++ct)
#pragma unroll
            for (int j = 0; j < 8; ++j)
                bfrag[kc][ct][j] = (short)f2bf(w[(kc * 32 + q * 8 + j) * HID + ct * 16 + m]);

    f32x4 acc[4] = {{0,0,0,0},{0,0,0,0},{0,0,0,0},{0,0,0,0}};

    int row = node_base + m;
    if (row >= NNODES) row = NNODES - 1;             // clamp (stores guarded)
    const float4* xp = (const float4*)(x + (size_t)row * IN_CH + q * 8);

#pragma unroll
    for (int kc = 0; kc < 4; ++kc) {
        float4 a0 = xp[kc * 8 + 0];
        float4 a1 = xp[kc * 8 + 1];
        s16x8 af;
        af[0] = (short)f2bf(a0.x); af[1] = (short)f2bf(a0.y);
        af[2] = (short)f2bf(a0.z); af[3] = (short)f2bf(a0.w);
        af[4] = (short)f2bf(a1.x); af[5] = (short)f2bf(a1.y);
        af[6] = (short)f2bf(a1.z); af[7] = (short)f2bf(a1.w);
#pragma unroll
        for (int ct = 0; ct < 4; ++ct)
            acc[ct] = __builtin_amdgcn_mfma_f32_16x16x32_bf16(af, bfrag[kc][ct], acc[ct], 0, 0, 0);
    }

#pragma unroll
    for (int ct = 0; ct < 4; ++ct) {
        int col = ct * 16 + m;
        float sc = g[col] * rsqrtf(var[col] + BN_EPS);
        float off = (bb[col] - mu[col]) * sc + be[col];
#pragma unroll
        for (int r = 0; r < 4; ++r) {
            int node = node_base + q * 4 + r;
            if (node < NNODES)
                h0[(size_t)node * HID + col] =
                    f2bf(fmaxf(acc[ct][r] * sc + off, 0.f));
        }
    }
}

// ---------------- K1: edge binning FUSED WITH fc matmul -------------------
// Bin blocks [0, BIN_BLOCKS): 1024 edges each (1 int4 per thread) -> 2x the
// latency-hiding block count vs R10. Flush coalesced, one global atomic per
// bin per block. fc blocks [BIN_BLOCKS, +MM): independent.
__global__ __launch_bounds__(256) void bin_fc(
        const int* __restrict__ src, const int* __restrict__ dst,
        unsigned int* __restrict__ staged, int* bin_n,
        int* slot, int* __restrict__ ell, int* ovf_n, int2* __restrict__ ovf,
        const float* __restrict__ x, const float* __restrict__ w,
        const float* __restrict__ bb,
        const float* __restrict__ g, const float* __restrict__ be,
        const float* __restrict__ mu, const float* __restrict__ var,
        ushort* __restrict__ h0) {
    __shared__ unsigned int sbin[BIN_N][BIN_CAP_LDS];   // 16 KB
    __shared__ int scnt[BIN_N];
    __shared__ int sbase[BIN_N];
    const int tid = threadIdx.x;

    if (blockIdx.x >= BIN_BLOCKS) {                     // ---- fc path ----
        fc_body(blockIdx.x - BIN_BLOCKS, tid, x, w, bb, g, be, mu, var, h0);
        return;
    }

    scnt[tid] = 0;                                      // BIN_N == blockDim
    __syncthreads();

    const int i = blockIdx.x * 256 + tid;               // int4 units
    const int4* dst4 = (const int4*)dst;
    const int4* src4 = (const int4*)src;
    if (i < NEDGES / 4) {                               // NEDGES % 4 == 0
        int4 dv = dst4[i];
        int4 sv = src4[i];
#define BIN_ONE(D, S)                                                       \
        {                                                                   \
            int b_ = (D) / BINW;                                            \
            unsigned int pk_ = ((unsigned int)((D) - b_ * BINW) << 17)      \
                               | (unsigned int)(S);                         \
            int sl_ = atomicAdd(&scnt[b_], 1);                              \
            if (sl_ < BIN_CAP_LDS) sbin[b_][sl_] = pk_;                     \
            else ell_insert((D), (S) << 7, slot, ell, ovf_n, ovf);          \
        }
        BIN_ONE(dv.x, sv.x)
        BIN_ONE(dv.y, sv.y)
        BIN_ONE(dv.z, sv.z)
        BIN_ONE(dv.w, sv.w)
#undef BIN_ONE
    }
    __syncthreads();
    {
        int c = scnt[tid];
        if (c > BIN_CAP_LDS) c = BIN_CAP_LDS;
        sbase[tid] = atomicAdd(&bin_n[tid], c);
    }
    __syncthreads();
    const int wave = tid >> 6;
    const int lane = tid & 63;
    for (int bb2 = wave; bb2 < BIN_N; bb2 += 4) {       // 64 bins per wave
        int c = scnt[bb2];
        if (c > BIN_CAP_LDS) c = BIN_CAP_LDS;
        if (lane < c) {
            int gidx = sbase[bb2] + lane;
            unsigned int v = sbin[bb2][lane];
            if (gidx < BIN_REGION) {
                staged[(size_t)bb2 * BIN_REGION + gidx] = v;
            } else {
                int d = bb2 * BINW + (int)(v >> 17);
                ell_insert(d, (int)(v & 0x1FFFFu) << 7, slot, ell, ovf_n, ovf);
            }
        }
    }
}

// ---------------- K2: per-bin ELL fill (1024 threads -> 4 waves/SIMD) -----
// One block per bin keeps the write-once-line exclusivity; 1024 threads
// (16 waves) give 4x the latency hiding of the 256-thread version. Each
// thread does ~5 independent atomic+store chains.
__global__ __launch_bounds__(1024) void ell_fill(
        const unsigned int* __restrict__ staged, const int* __restrict__ bin_n,
        int* slot, int* __restrict__ ell, int* ovf_n, int2* __restrict__ ovf) {
    const int b = blockIdx.x;
    int n = bin_n[b];
    if (n > BIN_REGION) n = BIN_REGION;
    const unsigned int* sp = staged + (size_t)b * BIN_REGION;
    const int lo = b * BINW;
    int i = threadIdx.x;
    for (; i + 3072 < n; i += 4096) {                   // 4 edges in flight
        unsigned int v0 = sp[i];
        unsigned int v1 = sp[i + 1024];
        unsigned int v2 = sp[i + 2048];
        unsigned int v3 = sp[i + 3072];
        ell_insert(lo + (int)(v0 >> 17), (int)(v0 & 0x1FFFFu) << 7, slot, ell, ovf_n, ovf);
        ell_insert(lo + (int)(v1 >> 17), (int)(v1 & 0x1FFFFu) << 7, slot, ell, ovf_n, ovf);
        ell_insert(lo + (int)(v2 >> 17), (int)(v2 & 0x1FFFFu) << 7, slot, ell, ovf_n, ovf);
        ell_insert(lo + (int)(v3 >> 17), (int)(v3 & 0x1FFFFu) << 7, slot, ell, ovf_n, ovf);
    }
    for (; i < n; i += 1024) {
        unsigned int v = sp[i];
        ell_insert(lo + (int)(v >> 17), (int)(v & 0x1FFFFu) << 7, slot, ell, ovf_n, ovf);
    }
}

// ---------------- K3: conv L1 (deg scale from slot) -----------------------
__global__ __launch_bounds__(256) void conv_mm_l1(
        const ushort* __restrict__ h, const float* __restrict__ w,
        const int* __restrict__ deg, ushort* __restrict__ hws) {
    const int tid = threadIdx.x;
    const int wave = tid >> 6;
    const int lane = tid & 63;
    const int m = lane & 15;
    const int q = lane >> 4;
    const int node_base = (blockIdx.x * 4 + wave) * 16;

    s16x8 bfrag[2][4];
#pragma unroll
    for (int kc = 0; kc < 2; ++kc)
#pragma unroll
        for (int ct = 0; ct < 4; ++ct)
#pragma unroll
            for (int j = 0; j < 8; ++j)
                bfrag[kc][ct][j] = (short)f2bf(w[(kc * 32 + q * 8 + j) * HID + ct * 16 + m]);

    f32x4 acc[4] = {{0,0,0,0},{0,0,0,0},{0,0,0,0},{0,0,0,0}};

    int row = node_base + m;
    if (row >= NNODES) row = NNODES - 1;

#pragma unroll
    for (int kc = 0; kc < 2; ++kc) {
        const s16x8* hp = (const s16x8*)(h + (size_t)row * HID + kc * 32 + q * 8);
        s16x8 af = *hp;
#pragma unroll
        for (int ct = 0; ct < 4; ++ct)
            acc[ct] = __builtin_amdgcn_mfma_f32_16x16x32_bf16(af, bfrag[kc][ct], acc[ct], 0, 0, 0);
    }

    float dv[4];
#pragma unroll
    for (int r = 0; r < 4; ++r) {
        int node = node_base + q * 4 + r;
        dv[r] = (node < NNODES) ? rsqrtf((float)(deg[node] + 1)) : 0.f;
    }
#pragma unroll
    for (int ct = 0; ct < 4; ++ct) {
#pragma unroll
        for (int r = 0; r < 4; ++r) {
            int node = node_base + q * 4 + r;
            if (node < NNODES)
                hws[(size_t)node * HID + ct * 16 + m] = f2bf(acc[ct][r] * dv[r]);
        }
    }
}

// ---------------- K4: gather L1 + epilogue + FUSED conv L2 ----------------
__global__ __launch_bounds__(256) void gather_conv(
        const ushort* __restrict__ hws,
        const int* __restrict__ deg, const int* __restrict__ ell,
        const int* __restrict__ ovf_n, const int2* __restrict__ ovf,
        const float* __restrict__ bias,
        const float* __restrict__ g, const float* __restrict__ be,
        const float* __restrict__ mu, const float* __restrict__ var,
        const ushort* __restrict__ last,
        const float* __restrict__ w2,
        ushort* __restrict__ hws2) {
    __shared__ ushort sh[32][72];                     // 4.6 KB, padded rows
    const int wave = threadIdx.x >> 6;
    const int lane = threadIdx.x & 63;
    const int grp  = lane >> 3;                       // row group 0..7
    const int j    = lane & 7;                        // 16 B sub-block
    const int d = blockIdx.x * 32 + wave * 8 + grp;   // 3125*32 = 100000 exact
    const unsigned int moff = (unsigned int)j * 16u;
    const unsigned int doff = ((unsigned int)d << 7) + moff;

    const char* hb = (const char*)hws;

    float a[8];
    {
        uint4 sv = *(const uint4*)(hb + doff);        // self-loop contribution
        a[0] = asf(sv.x << 16); a[1] = asf(sv.x & 0xffff0000u);
        a[2] = asf(sv.y << 16); a[3] = asf(sv.y & 0xffff0000u);
        a[4] = asf(sv.z << 16); a[5] = asf(sv.z & 0xffff0000u);
        a[6] = asf(sv.w << 16); a[7] = asf(sv.w & 0xffff0000u);
    }

#define ACC8(V)                                                         \
    a[0] += asf((V).x << 16); a[1] += asf((V).x & 0xffff0000u);         \
    a[2] += asf((V).y << 16); a[3] += asf((V).y & 0xffff0000u);         \
    a[4] += asf((V).z << 16); a[5] += asf((V).z & 0xffff0000u);         \
    a[6] += asf((V).w << 16); a[7] += asf((V).w & 0xffff0000u);

    const int n = deg[d];
    const int nn = (n < ELL_C) ? n : ELL_C;
    const int* sp = ell + ((size_t)d << 5);

    int k = 0;
    for (; k + 8 <= nn; k += 8) {                    // 8 x 16 B in flight
        unsigned int o0 = (unsigned int)sp[k + 0] + moff;
        unsigned int o1 = (unsigned int)sp[k + 1] + moff;
        unsigned int o2 = (unsigned int)sp[k + 2] + moff;
        unsigned int o3 = (unsigned int)sp[k + 3] + moff;
        unsigned int o4 = (unsigned int)sp[k + 4] + moff;
        unsigned int o5 = (unsigned int)sp[k + 5] + moff;
        unsigned int o6 = (unsigned int)sp[k + 6] + moff;
        unsigned int o7 = (unsigned int)sp[k + 7] + moff;
        uint4 v0 = *(const uint4*)(hb + o0);
        uint4 v1 = *(const uint4*)(hb + o1);
        uint4 v2 = *(const uint4*)(hb + o2);
        uint4 v3 = *(const uint4*)(hb + o3);
        uint4 v4 = *(const uint4*)(hb + o4);
        uint4 v5 = *(const uint4*)(hb + o5);
        uint4 v6 = *(const uint4*)(hb + o6);
        uint4 v7 = *(const uint4*)(hb + o7);
        ACC8(v0) ACC8(v1) ACC8(v2) ACC8(v3)
        ACC8(v4) ACC8(v5) ACC8(v6) ACC8(v7)
    }
    for (; k + 4 <= nn; k += 4) {
        unsigned int o0 = (unsigned int)sp[k + 0] + moff;
        unsigned int o1 = (unsigned int)sp[k + 1] + moff;
        unsigned int o2 = (unsigned int)sp[k + 2] + moff;
        unsigned int o3 = (unsigned int)sp[k + 3] + moff;
        uint4 v0 = *(const uint4*)(hb + o0);
        uint4 v1 = *(const uint4*)(hb + o1);
        uint4 v2 = *(const uint4*)(hb + o2);
        uint4 v3 = *(const uint4*)(hb + o3);
        ACC8(v0) ACC8(v1) ACC8(v2) ACC8(v3)
    }
    for (; k < nn; ++k) {
        uint4 v = *(const uint4*)(hb + ((unsigned int)sp[k] + moff));
        ACC8(v)
    }
    if (n > ELL_C) {                                 // rare overflow path
        int on = *ovf_n;
        if (on > OVF_CAP) on = OVF_CAP;
        for (int jj = 0; jj < on; ++jj) {
            int2 e = ovf[jj];
            if (e.x == d) {
                uint4 v = *(const uint4*)(hb + ((unsigned int)e.y + moff));
                ACC8(v)
            }
        }
    }
#undef ACC8

    float dd = rsqrtf((float)(n + 1));
    float4 bi0 = ((const float4*)bias)[2 * j], bi1 = ((const float4*)bias)[2 * j + 1];
    float4 g0  = ((const float4*)g)[2 * j],    g1  = ((const float4*)g)[2 * j + 1];
    float4 be0 = ((const float4*)be)[2 * j],   be1 = ((const float4*)be)[2 * j + 1];
    float4 mu0 = ((const float4*)mu)[2 * j],   mu1 = ((const float4*)mu)[2 * j + 1];
    float4 va0 = ((const float4*)var)[2 * j],  va1 = ((const float4*)var)[2 * j + 1];
    uint4 lv = *(const uint4*)((const char*)last + doff);
    float l0 = asf(lv.x << 16), l1 = asf(lv.x & 0xffff0000u);
    float l2 = asf(lv.y << 16), l3 = asf(lv.y & 0xffff0000u);
    float l4 = asf(lv.z << 16), l5 = asf(lv.z & 0xffff0000u);
    float l6 = asf(lv.w << 16), l7 = asf(lv.w & 0xffff0000u);

#define EPI(A, BI, GV, BE, MU, VA, LO) \
    (fmaxf(((A) * dd + (BI) - (MU)) * ((GV) * rsqrtf((VA) + BN_EPS)) + (BE), 0.f) + (LO))
    float r0 = EPI(a[0], bi0.x, g0.x, be0.x, mu0.x, va0.x, l0);
    float r1 = EPI(a[1], bi0.y, g0.y, be0.y, mu0.y, va0.y, l1);
    float r2 = EPI(a[2], bi0.z, g0.z, be0.z, mu0.z, va0.z, l2);
    float r3 = EPI(a[3], bi0.w, g0.w, be0.w, mu0.w, va0.w, l3);
    float r4 = EPI(a[4], bi1.x, g1.x, be1.x, mu1.x, va1.x, l4);
    float r5 = EPI(a[5], bi1.y, g1.y, be1.y, mu1.y, va1.y, l5);
    float r6 = EPI(a[6], bi1.z, g1.z, be1.z, mu1.z, va1.z, l6);
    float r7 = EPI(a[7], bi1.w, g1.w, be1.w, mu1.w, va1.w, l7);
#undef EPI

    // stash h1*dis (bf16) into LDS tile [32][72]
    {
        const int rloc = wave * 8 + grp;
        uint4 o;
        o.x = (unsigned int)f2bf(r0 * dd) | ((unsigned int)f2bf(r1 * dd) << 16);
        o.y = (unsigned int)f2bf(r2 * dd) | ((unsigned int)f2bf(r3 * dd) << 16);
        o.z = (unsigned int)f2bf(r4 * dd) | ((unsigned int)f2bf(r5 * dd) << 16);
        o.w = (unsigned int)f2bf(r6 * dd) | ((unsigned int)f2bf(r7 * dd) << 16);
        *(uint4*)(&sh[rloc][j * 8]) = o;
    }
    __syncthreads();

    // conv L2 on the LDS tile: wave w -> row-tile rt = w>>1, col tiles
    // ct = (w&1)*2 + {0,1}. 2 kc x 2 ct MFMAs per wave (16 total / block).
    {
        const int rt = wave >> 1;
        const int cbase = (wave & 1) * 2;
        const int m = lane & 15;
        const int q = lane >> 4;

        s16x8 bfrag[2][2];
#pragma unroll
        for (int kc = 0; kc < 2; ++kc)
#pragma unroll
            for (int c = 0; c < 2; ++c)
#pragma unroll
                for (int jj = 0; jj < 8; ++jj)
                    bfrag[kc][c][jj] = (short)f2bf(
                        w2[(kc * 32 + q * 8 + jj) * HID + (cbase + c) * 16 + m]);

        f32x4 acc2[2] = {{0,0,0,0},{0,0,0,0}};
#pragma unroll
        for (int kc = 0; kc < 2; ++kc) {
            s16x8 af = *(const s16x8*)(&sh[rt * 16 + m][kc * 32 + q * 8]);
#pragma unroll
            for (int c = 0; c < 2; ++c)
                acc2[c] = __builtin_amdgcn_mfma_f32_16x16x32_bf16(
                    af, bfrag[kc][c], acc2[c], 0, 0, 0);
        }

        const int node_base = blockIdx.x * 32 + rt * 16;
#pragma unroll
        for (int c = 0; c < 2; ++c) {
            const int col = (cbase + c) * 16 + m;
#pragma unroll
            for (int r = 0; r < 4; ++r) {
                int node = node_base + q * 4 + r;
                hws2[(size_t)node * HID + col] = f2bf(acc2[c][r]);
            }
        }
    }
}

// ---------------- K5: gather L2 + epilogue -> out (f32) -------------------
__global__ __launch_bounds__(256) void gather_update(
        const ushort* __restrict__ hws,
        const int* __restrict__ deg, const int* __restrict__ ell,
        const int* __restrict__ ovf_n, const int2* __restrict__ ovf,
        const float* __restrict__ bias,
        const float* __restrict__ g, const float* __restrict__ be,
        const float* __restrict__ mu, const float* __restrict__ var,
        const ushort* __restrict__ last,
        float* __restrict__ out_f) {
    const int wave = threadIdx.x >> 6;
    const int lane = threadIdx.x & 63;
    const int grp  = lane >> 3;
    const int j    = lane & 7;
    const int d = blockIdx.x * 32 + wave * 8 + grp;
    const unsigned int moff = (unsigned int)j * 16u;
    const unsigned int doff = ((unsigned int)d << 7) + moff;

    const char* hb = (const char*)hws;

    float a[8];
    {
        uint4 sv = *(const uint4*)(hb + doff);
        a[0] = asf(sv.x << 16); a[1] = asf(sv.x & 0xffff0000u);
        a[2] = asf(sv.y << 16); a[3] = asf(sv.y & 0xffff0000u);
        a[4] = asf(sv.z << 16); a[5] = asf(sv.z & 0xffff0000u);
        a[6] = asf(sv.w << 16); a[7] = asf(sv.w & 0xffff0000u);
    }

#define ACC8(V)                                                         \
    a[0] += asf((V).x << 16); a[1] += asf((V).x & 0xffff0000u);         \
    a[2] += asf((V).y << 16); a[3] += asf((V).y & 0xffff0000u);         \
    a[4] += asf((V).z << 16); a[5] += asf((V).z & 0xffff0000u);         \
    a[6] += asf((V).w << 16); a[7] += asf((V).w & 0xffff0000u);

    const int n = deg[d];
    const int nn = (n < ELL_C) ? n : ELL_C;
    const int* sp = ell + ((size_t)d << 5);

    int k = 0;
    for (; k + 8 <= nn; k += 8) {
        unsigned int o0 = (unsigned int)sp[k + 0] + moff;
        unsigned int o1 = (unsigned int)sp[k + 1] + moff;
        unsigned int o2 = (unsigned int)sp[k + 2] + moff;
        unsigned int o3 = (unsigned int)sp[k + 3] + moff;
        unsigned int o4 = (unsigned int)sp[k + 4] + moff;
        unsigned int o5 = (unsigned int)sp[k + 5] + moff;
        unsigned int o6 = (unsigned int)sp[k + 6] + moff;
        unsigned int o7 = (unsigned int)sp[k + 7] + moff;
        uint4 v0 = *(const uint4*)(hb + o0);
        uint4 v1 = *(const uint4*)(hb + o1);
        uint4 v2 = *(const uint4*)(hb + o2);
        uint4 v3 = *(const uint4*)(hb + o3);
        uint4 v4 = *(const uint4*)(hb + o4);
        uint4 v5 = *(const uint4*)(hb + o5);
        uint4 v6 = *(const uint4*)(hb + o6);
        uint4 v7 = *(const uint4*)(hb + o7);
        ACC8(v0) ACC8(v1) ACC8(v2) ACC8(v3)
        ACC8(v4) ACC8(v5) ACC8(v6) ACC8(v7)
    }
    for (; k + 4 <= nn; k += 4) {
        unsigned int o0 = (unsigned int)sp[k + 0] + moff;
        unsigned int o1 = (unsigned int)sp[k + 1] + moff;
        unsigned int o2 = (unsigned int)sp[k + 2] + moff;
        unsigned int o3 = (unsigned int)sp[k + 3] + moff;
        uint4 v0 = *(const uint4*)(hb + o0);
        uint4 v1 = *(const uint4*)(hb + o1);
        uint4 v2 = *(const uint4*)(hb + o2);
        uint4 v3 = *(const uint4*)(hb + o3);
        ACC8(v0) ACC8(v1) ACC8(v2) ACC8(v3)
    }
    for (; k < nn; ++k) {
        uint4 v = *(const uint4*)(hb + ((unsigned int)sp[k] + moff));
        ACC8(v)
    }
    if (n > ELL_C) {
        int on = *ovf_n;
        if (on > OVF_CAP) on = OVF_CAP;
        for (int jj = 0; jj < on; ++jj) {
            int2 e = ovf[jj];
            if (e.x == d) {
                uint4 v = *(const uint4*)(hb + ((unsigned int)e.y + moff));
                ACC8(v)
            }
        }
    }
#undef ACC8

    float dd = rsqrtf((float)(n + 1));
    float4 bi0 = ((const float4*)bias)[2 * j], bi1 = ((const float4*)bias)[2 * j + 1];
    float4 g0  = ((const float4*)g)[2 * j],    g1  = ((const float4*)g)[2 * j + 1];
    float4 be0 = ((const float4*)be)[2 * j],   be1 = ((const float4*)be)[2 * j + 1];
    float4 mu0 = ((const float4*)mu)[2 * j],   mu1 = ((const float4*)mu)[2 * j + 1];
    float4 va0 = ((const float4*)var)[2 * j],  va1 = ((const float4*)var)[2 * j + 1];
    uint4 lv = *(const uint4*)((const char*)last + doff);
    float l0 = asf(lv.x << 16), l1 = asf(lv.x & 0xffff0000u);
    float l2 = asf(lv.y << 16), l3 = asf(lv.y & 0xffff0000u);
    float l4 = asf(lv.z << 16), l5 = asf(lv.z & 0xffff0000u);
    float l6 = asf(lv.w << 16), l7 = asf(lv.w & 0xffff0000u);

#define EPI(A, BI, GV, BE, MU, VA, LO) \
    (fmaxf(((A) * dd + (BI) - (MU)) * ((GV) * rsqrtf((VA) + BN_EPS)) + (BE), 0.f) + (LO))
    float r0 = EPI(a[0], bi0.x, g0.x, be0.x, mu0.x, va0.x, l0);
    float r1 = EPI(a[1], bi0.y, g0.y, be0.y, mu0.y, va0.y, l1);
    float r2 = EPI(a[2], bi0.z, g0.z, be0.z, mu0.z, va0.z, l2);
    float r3 = EPI(a[3], bi0.w, g0.w, be0.w, mu0.w, va0.w, l3);
    float r4 = EPI(a[4], bi1.x, g1.x, be1.x, mu1.x, va1.x, l4);
    float r5 = EPI(a[5], bi1.y, g1.y, be1.y, mu1.y, va1.y, l5);
    float r6 = EPI(a[6], bi1.z, g1.z, be1.z, mu1.z, va1.z, l6);
    float r7 = EPI(a[7], bi1.w, g1.w, be1.w, mu1.w, va1.w, l7);
#undef EPI

    float4* op = (float4*)(out_f + (size_t)d * HID + j * 8);
    op[0] = make_float4(r0, r1, r2, r3);              // 32 B/lane, coalesced
    op[1] = make_float4(r4, r5, r6, r7);
}

extern "C" void kernel_launch(void* const* d_in, const int* in_sizes, int n_in,
                              void* d_out, int out_size, void* d_ws, size_t ws_size,
                              hipStream_t stream) {
    const float* x      = (const float*)d_in[0];
    const int*   eidx   = (const int*)d_in[1];
    const float* fc_w   = (const float*)d_in[2];
    const float* fc_b   = (const float*)d_in[3];
    const float* conv_w = (const float*)d_in[4];
    const float* conv_b = (const float*)d_in[5];
    const float* bn_g   = (const float*)d_in[6];
    const float* bn_b   = (const float*)d_in[7];
    const float* bn_m   = (const float*)d_in[8];
    const float* bn_v   = (const float*)d_in[9];

    const int* src = eidx;
    const int* dst = eidx + NEDGES;
    float* out = (float*)d_out;

    // workspace: slot | meta(ovf_n, pad, bin_n[256]) | ovf | ell |
    //            h0 | hws2 | hws | staged
    int*    slot    = (int*)d_ws;
    int*    meta    = slot + NPAD;                    // 272 ints
    int*    ovf_n   = meta;                           // meta[0]
    int*    bin_n   = meta + 16;                      // meta[16..271]
    int2*   ovf     = (int2*)(meta + 272);            // 8B-aligned
    int*    ell     = (int*)(ovf + OVF_CAP);          // N*32 ints = 12.8 MB
    ushort* h0      = (ushort*)(ell + (size_t)NNODES * ELL_C);  // N*64 bf16
    ushort* hws2    = h0 + (size_t)NNODES * HID;      // layer-2 gather source
    ushort* hws     = hws2 + (size_t)NNODES * HID;    // layer-1 gather source
    unsigned int* staged = (unsigned int*)(hws + (size_t)NNODES * HID);
                                                      // 256*10000*4 = 10.24 MB

    const int BLK = 256;

    // zero slot + meta in one async memset (adjacent)
    hipMemsetAsync(slot, 0, (size_t)(NPAD + 272) * 4, stream);

    // K1: read-once radix binning co-runs with fc -> h0
    bin_fc<<<BIN_BLOCKS + MM_BLOCKS, BLK, 0, stream>>>(
        src, dst, staged, bin_n, slot, ell, ovf_n, ovf,
        x, fc_w, fc_b, bn_g, bn_b, bn_m, bn_v, h0);

    // K2: per-bin ELL fill, 1024 thr/block -> 4x latency hiding
    ell_fill<<<BIN_N, 1024, 0, stream>>>(staged, bin_n, slot, ell, ovf_n, ovf);

    // K3: conv L1 (h0 -> hws, deg-scaled)
    conv_mm_l1<<<MM_BLOCKS, BLK, 0, stream>>>(h0, conv_w, slot, hws);

    // K4: gather L1 + conv L2 fused (hws -> hws2; h1 stays in LDS)
    gather_conv<<<GBLOCKS, BLK, 0, stream>>>(hws, slot, ell, ovf_n, ovf,
                                             conv_b, bn_g + HID, bn_b + HID,
                                             bn_m + HID, bn_v + HID, h0,
                                             conv_w + HID * HID, hws2);

    // K5: gather L2 -> out (f32)
    gather_update<<<GBLOCKS, BLK, 0, stream>>>(hws2, slot, ell, ovf_n, ovf,
                                               conv_b + HID, bn_g + 2 * HID, bn_b + 2 * HID,
                                               bn_m + 2 * HID, bn_v + 2 * HID,
                                               h0, out);
}

// Round 12
// 271.253 us; speedup vs baseline: 1.0585x; 1.0585x over previous
//
#include <hip/hip_runtime.h>

#define NNODES 100000
#define NEDGES 1250000
#define IN_CH 128
#define HID 64
#define BN_EPS 1e-5f

#define NPAD 100352               // NNODES rounded to 256 multiple
#define BIN_N 256                 // radix bins (391 nodes, 50 KB ELL slice)
#define BINW 391                  // ceil(NNODES / BIN_N); 256*391 = 100096
#define BIN_CHUNK 2048            // edges per block in pass-1 binning
#define BIN_BLOCKS 611            // ceil(NEDGES / BIN_CHUNK)
#define BIN_CAP_LDS 16            // per-block per-bin LDS cap (mean 8)
#define BIN_REGION 10000          // per-bin staged cap (mean 4883, 2x)
#define MM_BLOCKS 1563            // (NNODES+63)/64 MFMA matmul tiles
#define GBLOCKS 3125              // gather blocks: 32 rows each (4 waves x 8)
#define ELL_C 32                  // ELL bucket capacity (128 B = d<<7 bytes)
#define OVF_CAP 65536             // overflow list capacity (robustness only)

typedef __attribute__((ext_vector_type(8))) short s16x8;   // 8 bf16 (4 VGPRs)
typedef __attribute__((ext_vector_type(4))) float f32x4;

__device__ __forceinline__ ushort f2bf(float f) {
    union { float f; unsigned int i; } c;
    c.f = f;
    unsigned int lsb = (c.i >> 16) & 1u;
    return (ushort)((c.i + 0x7FFFu + lsb) >> 16);   // round-to-nearest-even
}
__device__ __forceinline__ float asf(unsigned int i) {
    union { unsigned int i; float f; } c;
    c.i = i;
    return c.f;
}

// ELL insert; slot[d] ends at FULL degree of d (increments past ELL_C),
// so slot doubles as the degree array after the fill phase.
__device__ __forceinline__ void ell_insert(int d, int soff, int* slot,
                                           int* ell, int* ovf_n, int2* ovf) {
    int s = atomicAdd(&slot[d], 1);
    if (s < ELL_C) ell[(d << 5) + s] = soff;
    else {
        int oi = atomicAdd(ovf_n, 1);
        if (oi < OVF_CAP) ovf[oi] = make_int2(d, soff);
    }
}

// ---------------- fc matmul body (MFMA, 16 nodes x 64 cols per wave) ------
__device__ __forceinline__ void fc_body(
        int blk, int tid,
        const float* __restrict__ x, const float* __restrict__ w,
        const float* __restrict__ bb,
        const float* __restrict__ g, const float* __restrict__ be,
        const float* __restrict__ mu, const float* __restrict__ var,
        ushort* __restrict__ h0) {
    const int wave = tid >> 6;
    const int lane = tid & 63;
    const int m = lane & 15;
    const int q = lane >> 4;
    const int node_base = (blk * 4 + wave) * 16;

    s16x8 bfrag[4][4];
#pragma unroll
    for (int kc = 0; kc < 4; ++kc)
#pragma unroll
        for (int ct = 0; ct < 4; ++ct)
#pragma unroll
            for (int j = 0; j < 8; ++j)
                bfrag[kc][ct][j] = (short)f2bf(w[(kc * 32 + q * 8 + j) * HID + ct * 16 + m]);

    f32x4 acc[4] = {{0,0,0,0},{0,0,0,0},{0,0,0,0},{0,0,0,0}};

    int row = node_base + m;
    if (row >= NNODES) row = NNODES - 1;             // clamp (stores guarded)
    const float4* xp = (const float4*)(x + (size_t)row * IN_CH + q * 8);

#pragma unroll
    for (int kc = 0; kc < 4; ++kc) {
        float4 a0 = xp[kc * 8 + 0];
        float4 a1 = xp[kc * 8 + 1];
        s16x8 af;
        af[0] = (short)f2bf(a0.x); af[1] = (short)f2bf(a0.y);
        af[2] = (short)f2bf(a0.z); af[3] = (short)f2bf(a0.w);
        af[4] = (short)f2bf(a1.x); af[5] = (short)f2bf(a1.y);
        af[6] = (short)f2bf(a1.z); af[7] = (short)f2bf(a1.w);
#pragma unroll
        for (int ct = 0; ct < 4; ++ct)
            acc[ct] = __builtin_amdgcn_mfma_f32_16x16x32_bf16(af, bfrag[kc][ct], acc[ct], 0, 0, 0);
    }

#pragma unroll
    for (int ct = 0; ct < 4; ++ct) {
        int col = ct * 16 + m;
        float sc = g[col] * rsqrtf(var[col] + BN_EPS);
        float off = (bb[col] - mu[col]) * sc + be[col];
#pragma unroll
        for (int r = 0; r < 4; ++r) {
            int node = node_base + q * 4 + r;
            if (node < NNODES)
                h0[(size_t)node * HID + col] =
                    f2bf(fmaxf(acc[ct][r] * sc + off, 0.f));
        }
    }
}

// ---------------- K1: edge binning FUSED WITH fc matmul -------------------
// Bin blocks [0, BIN_BLOCKS): 2048 edges each (R10-proven). Flush uses
// 4 bins x 16 lanes per wave-iteration (16 iters/wave vs 64): 4x fewer
// iterations, ~50% lane utilization at mean bin count 8, 256 B bursts.
// fc blocks [BIN_BLOCKS, +MM): independent (read x/w, write h0).
__global__ __launch_bounds__(256) void bin_fc(
        const int* __restrict__ src, const int* __restrict__ dst,
        unsigned int* __restrict__ staged, int* bin_n,
        int* slot, int* __restrict__ ell, int* ovf_n, int2* __restrict__ ovf,
        const float* __restrict__ x, const float* __restrict__ w,
        const float* __restrict__ bb,
        const float* __restrict__ g, const float* __restrict__ be,
        const float* __restrict__ mu, const float* __restrict__ var,
        ushort* __restrict__ h0) {
    __shared__ unsigned int sbin[BIN_N][BIN_CAP_LDS];   // 16 KB
    __shared__ int scnt[BIN_N];
    __shared__ int sbase[BIN_N];
    const int tid = threadIdx.x;

    if (blockIdx.x >= BIN_BLOCKS) {                     // ---- fc path ----
        fc_body(blockIdx.x - BIN_BLOCKS, tid, x, w, bb, g, be, mu, var, h0);
        return;
    }

    scnt[tid] = 0;                                      // BIN_N == blockDim
    __syncthreads();

    const int base = blockIdx.x * (BIN_CHUNK / 4);      // int4 units
    const int4* dst4 = (const int4*)dst;
    const int4* src4 = (const int4*)src;
#pragma unroll
    for (int k = 0; k < BIN_CHUNK / 1024; ++k) {        // 2 iters of 256 int4
        int i = base + k * 256 + tid;
        if (i < NEDGES / 4) {                           // NEDGES % 4 == 0
            int4 dv = dst4[i];
            int4 sv = src4[i];
#define BIN_ONE(D, S)                                                       \
            {                                                               \
                int b_ = (D) / BINW;                                        \
                unsigned int pk_ = ((unsigned int)((D) - b_ * BINW) << 17)  \
                                   | (unsigned int)(S);                     \
                int sl_ = atomicAdd(&scnt[b_], 1);                          \
                if (sl_ < BIN_CAP_LDS) sbin[b_][sl_] = pk_;                 \
                else ell_insert((D), (S) << 7, slot, ell, ovf_n, ovf);      \
            }
            BIN_ONE(dv.x, sv.x)
            BIN_ONE(dv.y, sv.y)
            BIN_ONE(dv.z, sv.z)
            BIN_ONE(dv.w, sv.w)
#undef BIN_ONE
        }
    }
    __syncthreads();
    {
        int c = scnt[tid];
        if (c > BIN_CAP_LDS) c = BIN_CAP_LDS;
        sbase[tid] = atomicAdd(&bin_n[tid], c);
    }
    __syncthreads();
    const int wave = tid >> 6;
    const int lane = tid & 63;
    // flush: each wave-iteration covers 4 bins x 16 slots (BIN_CAP_LDS)
    for (int grp = wave; grp < BIN_N / 4; grp += 4) {
        int b = grp * 4 + (lane >> 4);
        int s = lane & 15;
        int c = scnt[b];
        if (c > BIN_CAP_LDS) c = BIN_CAP_LDS;
        if (s < c) {
            int gidx = sbase[b] + s;
            unsigned int v = sbin[b][s];
            if (gidx < BIN_REGION) {
                staged[(size_t)b * BIN_REGION + gidx] = v;
            } else {
                int d = b * BINW + (int)(v >> 17);
                ell_insert(d, (int)(v & 0x1FFFFu) << 7, slot, ell, ovf_n, ovf);
            }
        }
    }
}

// ---------------- K2: per-bin ELL fill (1024 threads, bin-exclusive) ------
__global__ __launch_bounds__(1024) void ell_fill(
        const unsigned int* __restrict__ staged, const int* __restrict__ bin_n,
        int* slot, int* __restrict__ ell, int* ovf_n, int2* __restrict__ ovf) {
    const int b = blockIdx.x;
    int n = bin_n[b];
    if (n > BIN_REGION) n = BIN_REGION;
    const unsigned int* sp = staged + (size_t)b * BIN_REGION;
    const int lo = b * BINW;
    int i = threadIdx.x;
    for (; i + 3072 < n; i += 4096) {                   // 4 edges in flight
        unsigned int v0 = sp[i];
        unsigned int v1 = sp[i + 1024];
        unsigned int v2 = sp[i + 2048];
        unsigned int v3 = sp[i + 3072];
        ell_insert(lo + (int)(v0 >> 17), (int)(v0 & 0x1FFFFu) << 7, slot, ell, ovf_n, ovf);
        ell_insert(lo + (int)(v1 >> 17), (int)(v1 & 0x1FFFFu) << 7, slot, ell, ovf_n, ovf);
        ell_insert(lo + (int)(v2 >> 17), (int)(v2 & 0x1FFFFu) << 7, slot, ell, ovf_n, ovf);
        ell_insert(lo + (int)(v3 >> 17), (int)(v3 & 0x1FFFFu) << 7, slot, ell, ovf_n, ovf);
    }
    for (; i < n; i += 1024) {
        unsigned int v = sp[i];
        ell_insert(lo + (int)(v >> 17), (int)(v & 0x1FFFFu) << 7, slot, ell, ovf_n, ovf);
    }
}

// ---------------- K3: conv L1 (deg scale from slot) -----------------------
__global__ __launch_bounds__(256) void conv_mm_l1(
        const ushort* __restrict__ h, const float* __restrict__ w,
        const int* __restrict__ deg, ushort* __restrict__ hws) {
    const int tid = threadIdx.x;
    const int wave = tid >> 6;
    const int lane = tid & 63;
    const int m = lane & 15;
    const int q = lane >> 4;
    const int node_base = (blockIdx.x * 4 + wave) * 16;

    s16x8 bfrag[2][4];
#pragma unroll
    for (int kc = 0; kc < 2; ++kc)
#pragma unroll
        for (int ct = 0; ct < 4; ++ct)
#pragma unroll
            for (int j = 0; j < 8; ++j)
                bfrag[kc][ct][j] = (short)f2bf(w[(kc * 32 + q * 8 + j) * HID + ct * 16 + m]);

    f32x4 acc[4] = {{0,0,0,0},{0,0,0,0},{0,0,0,0},{0,0,0,0}};

    int row = node_base + m;
    if (row >= NNODES) row = NNODES - 1;

#pragma unroll
    for (int kc = 0; kc < 2; ++kc) {
        const s16x8* hp = (const s16x8*)(h + (size_t)row * HID + kc * 32 + q * 8);
        s16x8 af = *hp;
#pragma unroll
        for (int ct = 0; ct < 4; ++ct)
            acc[ct] = __builtin_amdgcn_mfma_f32_16x16x32_bf16(af, bfrag[kc][ct], acc[ct], 0, 0, 0);
    }

    float dv[4];
#pragma unroll
    for (int r = 0; r < 4; ++r) {
        int node = node_base + q * 4 + r;
        dv[r] = (node < NNODES) ? rsqrtf((float)(deg[node] + 1)) : 0.f;
    }
#pragma unroll
    for (int ct = 0; ct < 4; ++ct) {
#pragma unroll
        for (int r = 0; r < 4; ++r) {
            int node = node_base + q * 4 + r;
            if (node < NNODES)
                hws[(size_t)node * HID + ct * 16 + m] = f2bf(acc[ct][r] * dv[r]);
        }
    }
}

// ---------------- K4: gather L1 + epilogue + FUSED conv L2 ----------------
__global__ __launch_bounds__(256) void gather_conv(
        const ushort* __restrict__ hws,
        const int* __restrict__ deg, const int* __restrict__ ell,
        const int* __restrict__ ovf_n, const int2* __restrict__ ovf,
        const float* __restrict__ bias,
        const float* __restrict__ g, const float* __restrict__ be,
        const float* __restrict__ mu, const float* __restrict__ var,
        const ushort* __restrict__ last,
        const float* __restrict__ w2,
        ushort* __restrict__ hws2) {
    __shared__ ushort sh[32][72];                     // 4.6 KB, padded rows
    const int wave = threadIdx.x >> 6;
    const int lane = threadIdx.x & 63;
    const int grp  = lane >> 3;                       // row group 0..7
    const int j    = lane & 7;                        // 16 B sub-block
    const int d = blockIdx.x * 32 + wave * 8 + grp;   // 3125*32 = 100000 exact
    const unsigned int moff = (unsigned int)j * 16u;
    const unsigned int doff = ((unsigned int)d << 7) + moff;

    const char* hb = (const char*)hws;

    uint4 lv = *(const uint4*)((const char*)last + doff);   // issue early

    float a[8];
    {
        uint4 sv = *(const uint4*)(hb + doff);        // self-loop contribution
        a[0] = asf(sv.x << 16); a[1] = asf(sv.x & 0xffff0000u);
        a[2] = asf(sv.y << 16); a[3] = asf(sv.y & 0xffff0000u);
        a[4] = asf(sv.z << 16); a[5] = asf(sv.z & 0xffff0000u);
        a[6] = asf(sv.w << 16); a[7] = asf(sv.w & 0xffff0000u);
    }

#define ACC8(V)                                                         \
    a[0] += asf((V).x << 16); a[1] += asf((V).x & 0xffff0000u);         \
    a[2] += asf((V).y << 16); a[3] += asf((V).y & 0xffff0000u);         \
    a[4] += asf((V).z << 16); a[5] += asf((V).z & 0xffff0000u);         \
    a[6] += asf((V).w << 16); a[7] += asf((V).w & 0xffff0000u);

    const int n = deg[d];
    const int nn = (n < ELL_C) ? n : ELL_C;
    const int* sp = ell + ((size_t)d << 5);

    int k = 0;
    for (; k + 8 <= nn; k += 8) {                    // 8 x 16 B in flight
        unsigned int o0 = (unsigned int)sp[k + 0] + moff;
        unsigned int o1 = (unsigned int)sp[k + 1] + moff;
        unsigned int o2 = (unsigned int)sp[k + 2] + moff;
        unsigned int o3 = (unsigned int)sp[k + 3] + moff;
        unsigned int o4 = (unsigned int)sp[k + 4] + moff;
        unsigned int o5 = (unsigned int)sp[k + 5] + moff;
        unsigned int o6 = (unsigned int)sp[k + 6] + moff;
        unsigned int o7 = (unsigned int)sp[k + 7] + moff;
        uint4 v0 = *(const uint4*)(hb + o0);
        uint4 v1 = *(const uint4*)(hb + o1);
        uint4 v2 = *(const uint4*)(hb + o2);
        uint4 v3 = *(const uint4*)(hb + o3);
        uint4 v4 = *(const uint4*)(hb + o4);
        uint4 v5 = *(const uint4*)(hb + o5);
        uint4 v6 = *(const uint4*)(hb + o6);
        uint4 v7 = *(const uint4*)(hb + o7);
        ACC8(v0) ACC8(v1) ACC8(v2) ACC8(v3)
        ACC8(v4) ACC8(v5) ACC8(v6) ACC8(v7)
    }
    for (; k + 4 <= nn; k += 4) {
        unsigned int o0 = (unsigned int)sp[k + 0] + moff;
        unsigned int o1 = (unsigned int)sp[k + 1] + moff;
        unsigned int o2 = (unsigned int)sp[k + 2] + moff;
        unsigned int o3 = (unsigned int)sp[k + 3] + moff;
        uint4 v0 = *(const uint4*)(hb + o0);
        uint4 v1 = *(const uint4*)(hb + o1);
        uint4 v2 = *(const uint4*)(hb + o2);
        uint4 v3 = *(const uint4*)(hb + o3);
        ACC8(v0) ACC8(v1) ACC8(v2) ACC8(v3)
    }
    for (; k < nn; ++k) {
        uint4 v = *(const uint4*)(hb + ((unsigned int)sp[k] + moff));
        ACC8(v)
    }
    if (n > ELL_C) {                                 // rare overflow path
        int on = *ovf_n;
        if (on > OVF_CAP) on = OVF_CAP;
        for (int jj = 0; jj < on; ++jj) {
            int2 e = ovf[jj];
            if (e.x == d) {
                uint4 v = *(const uint4*)(hb + ((unsigned int)e.y + moff));
                ACC8(v)
            }
        }
    }
#undef ACC8

    float dd = rsqrtf((float)(n + 1));
    float4 bi0 = ((const float4*)bias)[2 * j], bi1 = ((const float4*)bias)[2 * j + 1];
    float4 g0  = ((const float4*)g)[2 * j],    g1  = ((const float4*)g)[2 * j + 1];
    float4 be0 = ((const float4*)be)[2 * j],   be1 = ((const float4*)be)[2 * j + 1];
    float4 mu0 = ((const float4*)mu)[2 * j],   mu1 = ((const float4*)mu)[2 * j + 1];
    float4 va0 = ((const float4*)var)[2 * j],  va1 = ((const float4*)var)[2 * j + 1];
    float l0 = asf(lv.x << 16), l1 = asf(lv.x & 0xffff0000u);
    float l2 = asf(lv.y << 16), l3 = asf(lv.y & 0xffff0000u);
    float l4 = asf(lv.z << 16), l5 = asf(lv.z & 0xffff0000u);
    float l6 = asf(lv.w << 16), l7 = asf(lv.w & 0xffff0000u);

#define EPI(A, BI, GV, BE, MU, VA, LO) \
    (fmaxf(((A) * dd + (BI) - (MU)) * ((GV) * rsqrtf((VA) + BN_EPS)) + (BE), 0.f) + (LO))
    float r0 = EPI(a[0], bi0.x, g0.x, be0.x, mu0.x, va0.x, l0);
    float r1 = EPI(a[1], bi0.y, g0.y, be0.y, mu0.y, va0.y, l1);
    float r2 = EPI(a[2], bi0.z, g0.z, be0.z, mu0.z, va0.z, l2);
    float r3 = EPI(a[3], bi0.w, g0.w, be0.w, mu0.w, va0.w, l3);
    float r4 = EPI(a[4], bi1.x, g1.x, be1.x, mu1.x, va1.x, l4);
    float r5 = EPI(a[5], bi1.y, g1.y, be1.y, mu1.y, va1.y, l5);
    float r6 = EPI(a[6], bi1.z, g1.z, be1.z, mu1.z, va1.z, l6);
    float r7 = EPI(a[7], bi1.w, g1.w, be1.w, mu1.w, va1.w, l7);
#undef EPI

    // stash h1*dis (bf16) into LDS tile [32][72]
    {
        const int rloc = wave * 8 + grp;
        uint4 o;
        o.x = (unsigned int)f2bf(r0 * dd) | ((unsigned int)f2bf(r1 * dd) << 16);
        o.y = (unsigned int)f2bf(r2 * dd) | ((unsigned int)f2bf(r3 * dd) << 16);
        o.z = (unsigned int)f2bf(r4 * dd) | ((unsigned int)f2bf(r5 * dd) << 16);
        o.w = (unsigned int)f2bf(r6 * dd) | ((unsigned int)f2bf(r7 * dd) << 16);
        *(uint4*)(&sh[rloc][j * 8]) = o;
    }
    __syncthreads();

    // conv L2 on the LDS tile: wave w -> row-tile rt = w>>1, col tiles
    // ct = (w&1)*2 + {0,1}. 2 kc x 2 ct MFMAs per wave (16 total / block).
    {
        const int rt = wave >> 1;
        const int cbase = (wave & 1) * 2;
        const int m = lane & 15;
        const int q = lane >> 4;

        s16x8 bfrag[2][2];
#pragma unroll
        for (int kc = 0; kc < 2; ++kc)
#pragma unroll
            for (int c = 0; c < 2; ++c)
#pragma unroll
                for (int jj = 0; jj < 8; ++jj)
                    bfrag[kc][c][jj] = (short)f2bf(
                        w2[(kc * 32 + q * 8 + jj) * HID + (cbase + c) * 16 + m]);

        f32x4 acc2[2] = {{0,0,0,0},{0,0,0,0}};
#pragma unroll
        for (int kc = 0; kc < 2; ++kc) {
            s16x8 af = *(const s16x8*)(&sh[rt * 16 + m][kc * 32 + q * 8]);
#pragma unroll
            for (int c = 0; c < 2; ++c)
                acc2[c] = __builtin_amdgcn_mfma_f32_16x16x32_bf16(
                    af, bfrag[kc][c], acc2[c], 0, 0, 0);
        }

        const int node_base = blockIdx.x * 32 + rt * 16;
#pragma unroll
        for (int c = 0; c < 2; ++c) {
            const int col = (cbase + c) * 16 + m;
#pragma unroll
            for (int r = 0; r < 4; ++r) {
                int node = node_base + q * 4 + r;
                hws2[(size_t)node * HID + col] = f2bf(acc2[c][r]);
            }
        }
    }
}

// ---------------- K5: gather L2 + epilogue -> out (f32) -------------------
__global__ __launch_bounds__(256) void gather_update(
        const ushort* __restrict__ hws,
        const int* __restrict__ deg, const int* __restrict__ ell,
        const int* __restrict__ ovf_n, const int2* __restrict__ ovf,
        const float* __restrict__ bias,
        const float* __restrict__ g, const float* __restrict__ be,
        const float* __restrict__ mu, const float* __restrict__ var,
        const ushort* __restrict__ last,
        float* __restrict__ out_f) {
    const int wave = threadIdx.x >> 6;
    const int lane = threadIdx.x & 63;
    const int grp  = lane >> 3;
    const int j    = lane & 7;
    const int d = blockIdx.x * 32 + wave * 8 + grp;
    const unsigned int moff = (unsigned int)j * 16u;
    const unsigned int doff = ((unsigned int)d << 7) + moff;

    const char* hb = (const char*)hws;

    uint4 lv = *(const uint4*)((const char*)last + doff);   // issue early

    float a[8];
    {
        uint4 sv = *(const uint4*)(hb + doff);
        a[0] = asf(sv.x << 16); a[1] = asf(sv.x & 0xffff0000u);
        a[2] = asf(sv.y << 16); a[3] = asf(sv.y & 0xffff0000u);
        a[4] = asf(sv.z << 16); a[5] = asf(sv.z & 0xffff0000u);
        a[6] = asf(sv.w << 16); a[7] = asf(sv.w & 0xffff0000u);
    }

#define ACC8(V)                                                         \
    a[0] += asf((V).x << 16); a[1] += asf((V).x & 0xffff0000u);         \
    a[2] += asf((V).y << 16); a[3] += asf((V).y & 0xffff0000u);         \
    a[4] += asf((V).z << 16); a[5] += asf((V).z & 0xffff0000u);         \
    a[6] += asf((V).w << 16); a[7] += asf((V).w & 0xffff0000u);

    const int n = deg[d];
    const int nn = (n < ELL_C) ? n : ELL_C;
    const int* sp = ell + ((size_t)d << 5);

    int k = 0;
    for (; k + 8 <= nn; k += 8) {
        unsigned int o0 = (unsigned int)sp[k + 0] + moff;
        unsigned int o1 = (unsigned int)sp[k + 1] + moff;
        unsigned int o2 = (unsigned int)sp[k + 2] + moff;
        unsigned int o3 = (unsigned int)sp[k + 3] + moff;
        unsigned int o4 = (unsigned int)sp[k + 4] + moff;
        unsigned int o5 = (unsigned int)sp[k + 5] + moff;
        unsigned int o6 = (unsigned int)sp[k + 6] + moff;
        unsigned int o7 = (unsigned int)sp[k + 7] + moff;
        uint4 v0 = *(const uint4*)(hb + o0);
        uint4 v1 = *(const uint4*)(hb + o1);
        uint4 v2 = *(const uint4*)(hb + o2);
        uint4 v3 = *(const uint4*)(hb + o3);
        uint4 v4 = *(const uint4*)(hb + o4);
        uint4 v5 = *(const uint4*)(hb + o5);
        uint4 v6 = *(const uint4*)(hb + o6);
        uint4 v7 = *(const uint4*)(hb + o7);
        ACC8(v0) ACC8(v1) ACC8(v2) ACC8(v3)
        ACC8(v4) ACC8(v5) ACC8(v6) ACC8(v7)
    }
    for (; k + 4 <= nn; k += 4) {
        unsigned int o0 = (unsigned int)sp[k + 0] + moff;
        unsigned int o1 = (unsigned int)sp[k + 1] + moff;
        unsigned int o2 = (unsigned int)sp[k + 2] + moff;
        unsigned int o3 = (unsigned int)sp[k + 3] + moff;
        uint4 v0 = *(const uint4*)(hb + o0);
        uint4 v1 = *(const uint4*)(hb + o1);
        uint4 v2 = *(const uint4*)(hb + o2);
        uint4 v3 = *(const uint4*)(hb + o3);
        ACC8(v0) ACC8(v1) ACC8(v2) ACC8(v3)
    }
    for (; k < nn; ++k) {
        uint4 v = *(const uint4*)(hb + ((unsigned int)sp[k] + moff));
        ACC8(v)
    }
    if (n > ELL_C) {
        int on = *ovf_n;
        if (on > OVF_CAP) on = OVF_CAP;
        for (int jj = 0; jj < on; ++jj) {
            int2 e = ovf[jj];
            if (e.x == d) {
                uint4 v = *(const uint4*)(hb + ((unsigned int)e.y + moff));
                ACC8(v)
            }
        }
    }
#undef ACC8

    float dd = rsqrtf((float)(n + 1));
    float4 bi0 = ((const float4*)bias)[2 * j], bi1 = ((const float4*)bias)[2 * j + 1];
    float4 g0  = ((const float4*)g)[2 * j],    g1  = ((const float4*)g)[2 * j + 1];
    float4 be0 = ((const float4*)be)[2 * j],   be1 = ((const float4*)be)[2 * j + 1];
    float4 mu0 = ((const float4*)mu)[2 * j],   mu1 = ((const float4*)mu)[2 * j + 1];
    float4 va0 = ((const float4*)var)[2 * j],  va1 = ((const float4*)var)[2 * j + 1];
    float l0 = asf(lv.x << 16), l1 = asf(lv.x & 0xffff0000u);
    float l2 = asf(lv.y << 16), l3 = asf(lv.y & 0xffff0000u);
    float l4 = asf(lv.z << 16), l5 = asf(lv.z & 0xffff0000u);
    float l6 = asf(lv.w << 16), l7 = asf(lv.w & 0xffff0000u);

#define EPI(A, BI, GV, BE, MU, VA, LO) \
    (fmaxf(((A) * dd + (BI) - (MU)) * ((GV) * rsqrtf((VA) + BN_EPS)) + (BE), 0.f) + (LO))
    float r0 = EPI(a[0], bi0.x, g0.x, be0.x, mu0.x, va0.x, l0);
    float r1 = EPI(a[1], bi0.y, g0.y, be0.y, mu0.y, va0.y, l1);
    float r2 = EPI(a[2], bi0.z, g0.z, be0.z, mu0.z, va0.z, l2);
    float r3 = EPI(a[3], bi0.w, g0.w, be0.w, mu0.w, va0.w, l3);
    float r4 = EPI(a[4], bi1.x, g1.x, be1.x, mu1.x, va1.x, l4);
    float r5 = EPI(a[5], bi1.y, g1.y, be1.y, mu1.y, va1.y, l5);
    float r6 = EPI(a[6], bi1.z, g1.z, be1.z, mu1.z, va1.z, l6);
    float r7 = EPI(a[7], bi1.w, g1.w, be1.w, mu1.w, va1.w, l7);
#undef EPI

    float4* op = (float4*)(out_f + (size_t)d * HID + j * 8);
    op[0] = make_float4(r0, r1, r2, r3);              // 32 B/lane, coalesced
    op[1] = make_float4(r4, r5, r6, r7);
}

extern "C" void kernel_launch(void* const* d_in, const int* in_sizes, int n_in,
                              void* d_out, int out_size, void* d_ws, size_t ws_size,
                              hipStream_t stream) {
    const float* x      = (const float*)d_in[0];
    const int*   eidx   = (const int*)d_in[1];
    const float* fc_w   = (const float*)d_in[2];
    const float* fc_b   = (const float*)d_in[3];
    const float* conv_w = (const float*)d_in[4];
    const float* conv_b = (const float*)d_in[5];
    const float* bn_g   = (const float*)d_in[6];
    const float* bn_b   = (const float*)d_in[7];
    const float* bn_m   = (const float*)d_in[8];
    const float* bn_v   = (const float*)d_in[9];

    const int* src = eidx;
    const int* dst = eidx + NEDGES;
    float* out = (float*)d_out;

    // workspace: slot | meta(ovf_n, pad, bin_n[256]) | ovf | ell |
    //            h0 | hws2 | hws | staged
    int*    slot    = (int*)d_ws;
    int*    meta    = slot + NPAD;                    // 272 ints
    int*    ovf_n   = meta;                           // meta[0]
    int*    bin_n   = meta + 16;                      // meta[16..271]
    int2*   ovf     = (int2*)(meta + 272);            // 8B-aligned
    int*    ell     = (int*)(ovf + OVF_CAP);          // N*32 ints = 12.8 MB
    ushort* h0      = (ushort*)(ell + (size_t)NNODES * ELL_C);  // N*64 bf16
    ushort* hws2    = h0 + (size_t)NNODES * HID;      // layer-2 gather source
    ushort* hws     = hws2 + (size_t)NNODES * HID;    // layer-1 gather source
    unsigned int* staged = (unsigned int*)(hws + (size_t)NNODES * HID);
                                                      // 256*10000*4 = 10.24 MB

    const int BLK = 256;

    // zero slot + meta in one async memset (adjacent)
    hipMemsetAsync(slot, 0, (size_t)(NPAD + 272) * 4, stream);

    // K1: read-once radix binning co-runs with fc -> h0
    bin_fc<<<BIN_BLOCKS + MM_BLOCKS, BLK, 0, stream>>>(
        src, dst, staged, bin_n, slot, ell, ovf_n, ovf,
        x, fc_w, fc_b, bn_g, bn_b, bn_m, bn_v, h0);

    // K2: per-bin ELL fill, 1024 thr/block
    ell_fill<<<BIN_N, 1024, 0, stream>>>(staged, bin_n, slot, ell, ovf_n, ovf);

    // K3: conv L1 (h0 -> hws, deg-scaled)
    conv_mm_l1<<<MM_BLOCKS, BLK, 0, stream>>>(h0, conv_w, slot, hws);

    // K4: gather L1 + conv L2 fused (hws -> hws2; h1 stays in LDS)
    gather_conv<<<GBLOCKS, BLK, 0, stream>>>(hws, slot, ell, ovf_n, ovf,
                                             conv_b, bn_g + HID, bn_b + HID,
                                             bn_m + HID, bn_v + HID, h0,
                                             conv_w + HID * HID, hws2);

    // K5: gather L2 -> out (f32)
    gather_update<<<GBLOCKS, BLK, 0, stream>>>(hws2, slot, ell, ovf_n, ovf,
                                               conv_b + HID, bn_g + 2 * HID, bn_b + 2 * HID,
                                               bn_m + 2 * HID, bn_v + 2 * HID,
                                               h0, out);
}

// Round 13
// 250.123 us; speedup vs baseline: 1.1479x; 1.0845x over previous
//
#include <hip/hip_runtime.h>

#define NNODES 100000
#define NEDGES 1250000
#define IN_CH 128
#define HID 64
#define BN_EPS 1e-5f

#define NPAD 100352               // NNODES rounded to 256 multiple
#define BIN_N 256                 // radix bins (391 nodes, 50 KB ELL slice)
#define BINW 391                  // ceil(NNODES / BIN_N); 256*391 = 100096
#define BIN_CHUNK 2048            // edges per block in pass-1 binning
#define BIN_BLOCKS 611            // ceil(NEDGES / BIN_CHUNK)
#define BIN_CAP_LDS 16            // per-block per-bin LDS cap (mean 8)
#define BIN_REGION 10000          // per-bin staged cap (mean 4883, 2x)
#define MM_BLOCKS 1563            // (NNODES+63)/64 MFMA matmul tiles (fc)
#define GBLOCKS 3125              // gather blocks: 32 rows each (4 waves x 8)
#define ELL_C 32                  // ELL bucket capacity (128 B = d<<7 bytes)
#define OVF_CAP 16384             // overflow list capacities (robustness)

typedef __attribute__((ext_vector_type(8))) short s16x8;   // 8 bf16 (4 VGPRs)
typedef __attribute__((ext_vector_type(4))) float f32x4;

__device__ __forceinline__ ushort f2bf(float f) {
    union { float f; unsigned int i; } c;
    c.f = f;
    unsigned int lsb = (c.i >> 16) & 1u;
    return (ushort)((c.i + 0x7FFFu + lsb) >> 16);   // round-to-nearest-even
}
__device__ __forceinline__ float asf(unsigned int i) {
    union { unsigned int i; float f; } c;
    c.i = i;
    return c.f;
}

// ---------------- fc matmul body (MFMA, 16 nodes x 64 cols per wave) ------
__device__ __forceinline__ void fc_body(
        int blk, int tid,
        const float* __restrict__ x, const float* __restrict__ w,
        const float* __restrict__ bb,
        const float* __restrict__ g, const float* __restrict__ be,
        const float* __restrict__ mu, const float* __restrict__ var,
        ushort* __restrict__ h0) {
    const int wave = tid >> 6;
    const int lane = tid & 63;
    const int m = lane & 15;
    const int q = lane >> 4;
    const int node_base = (blk * 4 + wave) * 16;

    s16x8 bfrag[4][4];
#pragma unroll
    for (int kc = 0; kc < 4; ++kc)
#pragma unroll
        for (int ct = 0; ct < 4; ++ct)
#pragma unroll
            for (int j = 0; j < 8; ++j)
                bfrag[kc][ct][j] = (short)f2bf(w[(kc * 32 + q * 8 + j) * HID + ct * 16 + m]);

    f32x4 acc[4] = {{0,0,0,0},{0,0,0,0},{0,0,0,0},{0,0,0,0}};

    int row = node_base + m;
    if (row >= NNODES) row = NNODES - 1;             // clamp (stores guarded)
    const float4* xp = (const float4*)(x + (size_t)row * IN_CH + q * 8);

#pragma unroll
    for (int kc = 0; kc < 4; ++kc) {
        float4 a0 = xp[kc * 8 + 0];
        float4 a1 = xp[kc * 8 + 1];
        s16x8 af;
        af[0] = (short)f2bf(a0.x); af[1] = (short)f2bf(a0.y);
        af[2] = (short)f2bf(a0.z); af[3] = (short)f2bf(a0.w);
        af[4] = (short)f2bf(a1.x); af[5] = (short)f2bf(a1.y);
        af[6] = (short)f2bf(a1.z); af[7] = (short)f2bf(a1.w);
#pragma unroll
        for (int ct = 0; ct < 4; ++ct)
            acc[ct] = __builtin_amdgcn_mfma_f32_16x16x32_bf16(af, bfrag[kc][ct], acc[ct], 0, 0, 0);
    }

#pragma unroll
    for (int ct = 0; ct < 4; ++ct) {
        int col = ct * 16 + m;
        float sc = g[col] * rsqrtf(var[col] + BN_EPS);
        float off = (bb[col] - mu[col]) * sc + be[col];
#pragma unroll
        for (int r = 0; r < 4; ++r) {
            int node = node_base + q * 4 + r;
            if (node < NNODES)
                h0[(size_t)node * HID + col] =
                    f2bf(fmaxf(acc[ct][r] * sc + off, 0.f));
        }
    }
}

// ---------------- K1: edge binning FUSED WITH fc matmul -------------------
// Bin blocks: 2048 edges each, radix-bin into 256 LDS bins, flush coalesced
// (4 bins x 16 lanes per wave-iter). Fallbacks (LDS-cap or staged-cap
// overflow, ~2K edges expected) append to the ovf1 LIST only -- bin_fc
// never touches slot[]/ell[] (they are written exclusively by fill_conv).
// fc blocks [BIN_BLOCKS, +MM): independent (read x/w, write h0).
__global__ __launch_bounds__(256) void bin_fc(
        const int* __restrict__ src, const int* __restrict__ dst,
        unsigned int* __restrict__ staged, int* bin_n,
        int* ovf1_n, int2* __restrict__ ovf1,
        const float* __restrict__ x, const float* __restrict__ w,
        const float* __restrict__ bb,
        const float* __restrict__ g, const float* __restrict__ be,
        const float* __restrict__ mu, const float* __restrict__ var,
        ushort* __restrict__ h0) {
    __shared__ unsigned int sbin[BIN_N][BIN_CAP_LDS];   // 16 KB
    __shared__ int scnt[BIN_N];
    __shared__ int sbase[BIN_N];
    const int tid = threadIdx.x;

    if (blockIdx.x >= BIN_BLOCKS) {                     // ---- fc path ----
        fc_body(blockIdx.x - BIN_BLOCKS, tid, x, w, bb, g, be, mu, var, h0);
        return;
    }

    scnt[tid] = 0;                                      // BIN_N == blockDim
    __syncthreads();

    const int base = blockIdx.x * (BIN_CHUNK / 4);      // int4 units
    const int4* dst4 = (const int4*)dst;
    const int4* src4 = (const int4*)src;
#pragma unroll
    for (int k = 0; k < BIN_CHUNK / 1024; ++k) {        // 2 iters of 256 int4
        int i = base + k * 256 + tid;
        if (i < NEDGES / 4) {                           // NEDGES % 4 == 0
            int4 dv = dst4[i];
            int4 sv = src4[i];
#define BIN_ONE(D, S)                                                       \
            {                                                               \
                int b_ = (D) / BINW;                                        \
                unsigned int pk_ = ((unsigned int)((D) - b_ * BINW) << 17)  \
                                   | (unsigned int)(S);                     \
                int sl_ = atomicAdd(&scnt[b_], 1);                          \
                if (sl_ < BIN_CAP_LDS) sbin[b_][sl_] = pk_;                 \
                else {                                                      \
                    int oi_ = atomicAdd(ovf1_n, 1);                         \
                    if (oi_ < OVF_CAP) ovf1[oi_] = make_int2((D), (S) << 7);\
                }                                                           \
            }
            BIN_ONE(dv.x, sv.x)
            BIN_ONE(dv.y, sv.y)
            BIN_ONE(dv.z, sv.z)
            BIN_ONE(dv.w, sv.w)
#undef BIN_ONE
        }
    }
    __syncthreads();
    {
        int c = scnt[tid];
        if (c > BIN_CAP_LDS) c = BIN_CAP_LDS;
        sbase[tid] = atomicAdd(&bin_n[tid], c);
    }
    __syncthreads();
    const int wave = tid >> 6;
    const int lane = tid & 63;
    // flush: each wave-iteration covers 4 bins x 16 slots (BIN_CAP_LDS)
    for (int grp = wave; grp < BIN_N / 4; grp += 4) {
        int b = grp * 4 + (lane >> 4);
        int s = lane & 15;
        int c = scnt[b];
        if (c > BIN_CAP_LDS) c = BIN_CAP_LDS;
        if (s < c) {
            int gidx = sbase[b] + s;
            unsigned int v = sbin[b][s];
            if (gidx < BIN_REGION) {
                staged[(size_t)b * BIN_REGION + gidx] = v;
            } else {
                int d = b * BINW + (int)(v >> 17);
                int oi = atomicAdd(ovf1_n, 1);
                if (oi < OVF_CAP) ovf1[oi] = make_int2(d, (int)(v & 0x1FFFFu) << 7);
            }
        }
    }
}

// ---------------- K2: per-bin ELL fill + FUSED conv L1 --------------------
// One block per bin, 1024 threads. Fill counts in LDS (no global atomics):
// block b exclusively owns nodes [lo, hi) so after __syncthreads it knows
// FINAL degrees locally -> writes slot[] non-atomically (no memset needed)
// and runs conv L1 for its own 391 nodes with the deg scale read from LDS.
// Removes the conv_mm_l1 dispatch AND ell_fill's atomic serialization.
__global__ __launch_bounds__(1024) void fill_conv(
        const unsigned int* __restrict__ staged, const int* __restrict__ bin_n,
        const int* __restrict__ ovf1_n, const int2* __restrict__ ovf1,
        int* __restrict__ slot, int* __restrict__ ell,
        int* ovf2_n, int2* __restrict__ ovf2,
        const ushort* __restrict__ h0, const float* __restrict__ w1,
        ushort* __restrict__ hws) {
    __shared__ int cnt[BINW];
    const int tid = threadIdx.x;
    const int b = blockIdx.x;
    const int lo = b * BINW;
    const int hi = (lo + BINW < NNODES) ? lo + BINW : NNODES;  // exclusive

    for (int v = tid; v < BINW; v += 1024) cnt[v] = 0;
    __syncthreads();

#define INS(DL, SOFF)                                                       \
    {                                                                       \
        int s_ = atomicAdd(&cnt[(DL)], 1);                                  \
        if (s_ < ELL_C) ell[((lo + (DL)) << 5) + s_] = (SOFF);              \
        else {                                                              \
            int oi_ = atomicAdd(ovf2_n, 1);                                 \
            if (oi_ < OVF_CAP) ovf2[oi_] = make_int2(lo + (DL), (SOFF));    \
        }                                                                   \
    }
    // staged entries for this bin
    {
        int n = bin_n[b];
        if (n > BIN_REGION) n = BIN_REGION;
        const unsigned int* sp = staged + (size_t)b * BIN_REGION;
        int i = tid;
        for (; i + 3072 < n; i += 4096) {               // 4 in flight
            unsigned int v0 = sp[i];
            unsigned int v1 = sp[i + 1024];
            unsigned int v2 = sp[i + 2048];
            unsigned int v3 = sp[i + 3072];
            INS((int)(v0 >> 17), (int)(v0 & 0x1FFFFu) << 7)
            INS((int)(v1 >> 17), (int)(v1 & 0x1FFFFu) << 7)
            INS((int)(v2 >> 17), (int)(v2 & 0x1FFFFu) << 7)
            INS((int)(v3 >> 17), (int)(v3 & 0x1FFFFu) << 7)
        }
        for (; i < n; i += 1024) {
            unsigned int v = sp[i];
            INS((int)(v >> 17), (int)(v & 0x1FFFFu) << 7)
        }
    }
    // fallback list from bin_fc (tiny): pick entries in our range
    {
        int on = *ovf1_n;
        if (on > OVF_CAP) on = OVF_CAP;
        for (int i = tid; i < on; i += 1024) {
            int2 e = ovf1[i];
            if (e.x >= lo && e.x < hi) INS(e.x - lo, e.y)
        }
    }
#undef INS
    __syncthreads();

    // publish final degrees (exclusive range -> plain stores)
    for (int v = tid; v < hi - lo; v += 1024) slot[lo + v] = cnt[v];

    // ---- conv L1 for this bin's nodes: hws = (h0 @ W1) * rsqrt(deg+1) ----
    const int wave = tid >> 6;                        // 0..15
    const int lane = tid & 63;
    const int m = lane & 15;
    const int q = lane >> 4;

    s16x8 bfrag[2][4];
#pragma unroll
    for (int kc = 0; kc < 2; ++kc)
#pragma unroll
        for (int ct = 0; ct < 4; ++ct)
#pragma unroll
            for (int j = 0; j < 8; ++j)
                bfrag[kc][ct][j] = (short)f2bf(w1[(kc * 32 + q * 8 + j) * HID + ct * 16 + m]);

#pragma unroll
    for (int pass = 0; pass < 2; ++pass) {
        const int nb16 = lo + pass * 256 + wave * 16; // wave-uniform
        if (nb16 >= hi) continue;

        f32x4 acc[4] = {{0,0,0,0},{0,0,0,0},{0,0,0,0},{0,0,0,0}};
        int row = nb16 + m;
        if (row >= hi) row = hi - 1;                  // clamp (stores guarded)
#pragma unroll
        for (int kc = 0; kc < 2; ++kc) {
            const s16x8* hp = (const s16x8*)(h0 + (size_t)row * HID + kc * 32 + q * 8);
            s16x8 af = *hp;
#pragma unroll
            for (int ct = 0; ct < 4; ++ct)
                acc[ct] = __builtin_amdgcn_mfma_f32_16x16x32_bf16(af, bfrag[kc][ct], acc[ct], 0, 0, 0);
        }

        float dv[4];
#pragma unroll
        for (int r = 0; r < 4; ++r) {
            int node = nb16 + q * 4 + r;
            dv[r] = (node < hi) ? rsqrtf((float)(cnt[node - lo] + 1)) : 0.f;
        }
#pragma unroll
        for (int ct = 0; ct < 4; ++ct) {
#pragma unroll
            for (int r = 0; r < 4; ++r) {
                int node = nb16 + q * 4 + r;
                if (node < hi)
                    hws[(size_t)node * HID + ct * 16 + m] = f2bf(acc[ct][r] * dv[r]);
            }
        }
    }
}

// ---------------- K3: gather L1 + epilogue + FUSED conv L2 ----------------
__global__ __launch_bounds__(256) void gather_conv(
        const ushort* __restrict__ hws,
        const int* __restrict__ deg, const int* __restrict__ ell,
        const int* __restrict__ ovf_n, const int2* __restrict__ ovf,
        const float* __restrict__ bias,
        const float* __restrict__ g, const float* __restrict__ be,
        const float* __restrict__ mu, const float* __restrict__ var,
        const ushort* __restrict__ last,
        const float* __restrict__ w2,
        ushort* __restrict__ hws2) {
    __shared__ ushort sh[32][72];                     // 4.6 KB, padded rows
    const int wave = threadIdx.x >> 6;
    const int lane = threadIdx.x & 63;
    const int grp  = lane >> 3;                       // row group 0..7
    const int j    = lane & 7;                        // 16 B sub-block
    const int d = blockIdx.x * 32 + wave * 8 + grp;   // 3125*32 = 100000 exact
    const unsigned int moff = (unsigned int)j * 16u;
    const unsigned int doff = ((unsigned int)d << 7) + moff;

    const char* hb = (const char*)hws;

    uint4 lv = *(const uint4*)((const char*)last + doff);   // issue early

    float a[8];
    {
        uint4 sv = *(const uint4*)(hb + doff);        // self-loop contribution
        a[0] = asf(sv.x << 16); a[1] = asf(sv.x & 0xffff0000u);
        a[2] = asf(sv.y << 16); a[3] = asf(sv.y & 0xffff0000u);
        a[4] = asf(sv.z << 16); a[5] = asf(sv.z & 0xffff0000u);
        a[6] = asf(sv.w << 16); a[7] = asf(sv.w & 0xffff0000u);
    }

#define ACC8(V)                                                         \
    a[0] += asf((V).x << 16); a[1] += asf((V).x & 0xffff0000u);         \
    a[2] += asf((V).y << 16); a[3] += asf((V).y & 0xffff0000u);         \
    a[4] += asf((V).z << 16); a[5] += asf((V).z & 0xffff0000u);         \
    a[6] += asf((V).w << 16); a[7] += asf((V).w & 0xffff0000u);

    const int n = deg[d];
    const int nn = (n < ELL_C) ? n : ELL_C;
    const int* sp = ell + ((size_t)d << 5);

    int k = 0;
    for (; k + 8 <= nn; k += 8) {                    // 8 x 16 B in flight
        unsigned int o0 = (unsigned int)sp[k + 0] + moff;
        unsigned int o1 = (unsigned int)sp[k + 1] + moff;
        unsigned int o2 = (unsigned int)sp[k + 2] + moff;
        unsigned int o3 = (unsigned int)sp[k + 3] + moff;
        unsigned int o4 = (unsigned int)sp[k + 4] + moff;
        unsigned int o5 = (unsigned int)sp[k + 5] + moff;
        unsigned int o6 = (unsigned int)sp[k + 6] + moff;
        unsigned int o7 = (unsigned int)sp[k + 7] + moff;
        uint4 v0 = *(const uint4*)(hb + o0);
        uint4 v1 = *(const uint4*)(hb + o1);
        uint4 v2 = *(const uint4*)(hb + o2);
        uint4 v3 = *(const uint4*)(hb + o3);
        uint4 v4 = *(const uint4*)(hb + o4);
        uint4 v5 = *(const uint4*)(hb + o5);
        uint4 v6 = *(const uint4*)(hb + o6);
        uint4 v7 = *(const uint4*)(hb + o7);
        ACC8(v0) ACC8(v1) ACC8(v2) ACC8(v3)
        ACC8(v4) ACC8(v5) ACC8(v6) ACC8(v7)
    }
    for (; k + 4 <= nn; k += 4) {
        unsigned int o0 = (unsigned int)sp[k + 0] + moff;
        unsigned int o1 = (unsigned int)sp[k + 1] + moff;
        unsigned int o2 = (unsigned int)sp[k + 2] + moff;
        unsigned int o3 = (unsigned int)sp[k + 3] + moff;
        uint4 v0 = *(const uint4*)(hb + o0);
        uint4 v1 = *(const uint4*)(hb + o1);
        uint4 v2 = *(const uint4*)(hb + o2);
        uint4 v3 = *(const uint4*)(hb + o3);
        ACC8(v0) ACC8(v1) ACC8(v2) ACC8(v3)
    }
    for (; k < nn; ++k) {
        uint4 v = *(const uint4*)(hb + ((unsigned int)sp[k] + moff));
        ACC8(v)
    }
    if (n > ELL_C) {                                 // rare overflow path
        int on = *ovf_n;
        if (on > OVF_CAP) on = OVF_CAP;
        for (int jj = 0; jj < on; ++jj) {
            int2 e = ovf[jj];
            if (e.x == d) {
                uint4 v = *(const uint4*)(hb + ((unsigned int)e.y + moff));
                ACC8(v)
            }
        }
    }
#undef ACC8

    float dd = rsqrtf((float)(n + 1));
    float4 bi0 = ((const float4*)bias)[2 * j], bi1 = ((const float4*)bias)[2 * j + 1];
    float4 g0  = ((const float4*)g)[2 * j],    g1  = ((const float4*)g)[2 * j + 1];
    float4 be0 = ((const float4*)be)[2 * j],   be1 = ((const float4*)be)[2 * j + 1];
    float4 mu0 = ((const float4*)mu)[2 * j],   mu1 = ((const float4*)mu)[2 * j + 1];
    float4 va0 = ((const float4*)var)[2 * j],  va1 = ((const float4*)var)[2 * j + 1];
    float l0 = asf(lv.x << 16), l1 = asf(lv.x & 0xffff0000u);
    float l2 = asf(lv.y << 16), l3 = asf(lv.y & 0xffff0000u);
    float l4 = asf(lv.z << 16), l5 = asf(lv.z & 0xffff0000u);
    float l6 = asf(lv.w << 16), l7 = asf(lv.w & 0xffff0000u);

#define EPI(A, BI, GV, BE, MU, VA, LO) \
    (fmaxf(((A) * dd + (BI) - (MU)) * ((GV) * rsqrtf((VA) + BN_EPS)) + (BE), 0.f) + (LO))
    float r0 = EPI(a[0], bi0.x, g0.x, be0.x, mu0.x, va0.x, l0);
    float r1 = EPI(a[1], bi0.y, g0.y, be0.y, mu0.y, va0.y, l1);
    float r2 = EPI(a[2], bi0.z, g0.z, be0.z, mu0.z, va0.z, l2);
    float r3 = EPI(a[3], bi0.w, g0.w, be0.w, mu0.w, va0.w, l3);
    float r4 = EPI(a[4], bi1.x, g1.x, be1.x, mu1.x, va1.x, l4);
    float r5 = EPI(a[5], bi1.y, g1.y, be1.y, mu1.y, va1.y, l5);
    float r6 = EPI(a[6], bi1.z, g1.z, be1.z, mu1.z, va1.z, l6);
    float r7 = EPI(a[7], bi1.w, g1.w, be1.w, mu1.w, va1.w, l7);
#undef EPI

    // stash h1*dis (bf16) into LDS tile [32][72]
    {
        const int rloc = wave * 8 + grp;
        uint4 o;
        o.x = (unsigned int)f2bf(r0 * dd) | ((unsigned int)f2bf(r1 * dd) << 16);
        o.y = (unsigned int)f2bf(r2 * dd) | ((unsigned int)f2bf(r3 * dd) << 16);
        o.z = (unsigned int)f2bf(r4 * dd) | ((unsigned int)f2bf(r5 * dd) << 16);
        o.w = (unsigned int)f2bf(r6 * dd) | ((unsigned int)f2bf(r7 * dd) << 16);
        *(uint4*)(&sh[rloc][j * 8]) = o;
    }
    __syncthreads();

    // conv L2 on the LDS tile: wave w -> row-tile rt = w>>1, col tiles
    // ct = (w&1)*2 + {0,1}. 2 kc x 2 ct MFMAs per wave (16 total / block).
    {
        const int rt = wave >> 1;
        const int cbase = (wave & 1) * 2;
        const int m = lane & 15;
        const int q = lane >> 4;

        s16x8 bfrag[2][2];
#pragma unroll
        for (int kc = 0; kc < 2; ++kc)
#pragma unroll
            for (int c = 0; c < 2; ++c)
#pragma unroll
                for (int jj = 0; jj < 8; ++jj)
                    bfrag[kc][c][jj] = (short)f2bf(
                        w2[(kc * 32 + q * 8 + jj) * HID + (cbase + c) * 16 + m]);

        f32x4 acc2[2] = {{0,0,0,0},{0,0,0,0}};
#pragma unroll
        for (int kc = 0; kc < 2; ++kc) {
            s16x8 af = *(const s16x8*)(&sh[rt * 16 + m][kc * 32 + q * 8]);
#pragma unroll
            for (int c = 0; c < 2; ++c)
                acc2[c] = __builtin_amdgcn_mfma_f32_16x16x32_bf16(
                    af, bfrag[kc][c], acc2[c], 0, 0, 0);
        }

        const int node_base = blockIdx.x * 32 + rt * 16;
#pragma unroll
        for (int c = 0; c < 2; ++c) {
            const int col = (cbase + c) * 16 + m;
#pragma unroll
            for (int r = 0; r < 4; ++r) {
                int node = node_base + q * 4 + r;
                hws2[(size_t)node * HID + col] = f2bf(acc2[c][r]);
            }
        }
    }
}

// ---------------- K4: gather L2 + epilogue -> out (f32) -------------------
__global__ __launch_bounds__(256) void gather_update(
        const ushort* __restrict__ hws,
        const int* __restrict__ deg, const int* __restrict__ ell,
        const int* __restrict__ ovf_n, const int2* __restrict__ ovf,
        const float* __restrict__ bias,
        const float* __restrict__ g, const float* __restrict__ be,
        const float* __restrict__ mu, const float* __restrict__ var,
        const ushort* __restrict__ last,
        float* __restrict__ out_f) {
    const int wave = threadIdx.x >> 6;
    const int lane = threadIdx.x & 63;
    const int grp  = lane >> 3;
    const int j    = lane & 7;
    const int d = blockIdx.x * 32 + wave * 8 + grp;
    const unsigned int moff = (unsigned int)j * 16u;
    const unsigned int doff = ((unsigned int)d << 7) + moff;

    const char* hb = (const char*)hws;

    uint4 lv = *(const uint4*)((const char*)last + doff);   // issue early

    float a[8];
    {
        uint4 sv = *(const uint4*)(hb + doff);
        a[0] = asf(sv.x << 16); a[1] = asf(sv.x & 0xffff0000u);
        a[2] = asf(sv.y << 16); a[3] = asf(sv.y & 0xffff0000u);
        a[4] = asf(sv.z << 16); a[5] = asf(sv.z & 0xffff0000u);
        a[6] = asf(sv.w << 16); a[7] = asf(sv.w & 0xffff0000u);
    }

#define ACC8(V)                                                         \
    a[0] += asf((V).x << 16); a[1] += asf((V).x & 0xffff0000u);         \
    a[2] += asf((V).y << 16); a[3] += asf((V).y & 0xffff0000u);         \
    a[4] += asf((V).z << 16); a[5] += asf((V).z & 0xffff0000u);         \
    a[6] += asf((V).w << 16); a[7] += asf((V).w & 0xffff0000u);

    const int n = deg[d];
    const int nn = (n < ELL_C) ? n : ELL_C;
    const int* sp = ell + ((size_t)d << 5);

    int k = 0;
    for (; k + 8 <= nn; k += 8) {
        unsigned int o0 = (unsigned int)sp[k + 0] + moff;
        unsigned int o1 = (unsigned int)sp[k + 1] + moff;
        unsigned int o2 = (unsigned int)sp[k + 2] + moff;
        unsigned int o3 = (unsigned int)sp[k + 3] + moff;
        unsigned int o4 = (unsigned int)sp[k + 4] + moff;
        unsigned int o5 = (unsigned int)sp[k + 5] + moff;
        unsigned int o6 = (unsigned int)sp[k + 6] + moff;
        unsigned int o7 = (unsigned int)sp[k + 7] + moff;
        uint4 v0 = *(const uint4*)(hb + o0);
        uint4 v1 = *(const uint4*)(hb + o1);
        uint4 v2 = *(const uint4*)(hb + o2);
        uint4 v3 = *(const uint4*)(hb + o3);
        uint4 v4 = *(const uint4*)(hb + o4);
        uint4 v5 = *(const uint4*)(hb + o5);
        uint4 v6 = *(const uint4*)(hb + o6);
        uint4 v7 = *(const uint4*)(hb + o7);
        ACC8(v0) ACC8(v1) ACC8(v2) ACC8(v3)
        ACC8(v4) ACC8(v5) ACC8(v6) ACC8(v7)
    }
    for (; k + 4 <= nn; k += 4) {
        unsigned int o0 = (unsigned int)sp[k + 0] + moff;
        unsigned int o1 = (unsigned int)sp[k + 1] + moff;
        unsigned int o2 = (unsigned int)sp[k + 2] + moff;
        unsigned int o3 = (unsigned int)sp[k + 3] + moff;
        uint4 v0 = *(const uint4*)(hb + o0);
        uint4 v1 = *(const uint4*)(hb + o1);
        uint4 v2 = *(const uint4*)(hb + o2);
        uint4 v3 = *(const uint4*)(hb + o3);
        ACC8(v0) ACC8(v1) ACC8(v2) ACC8(v3)
    }
    for (; k < nn; ++k) {
        uint4 v = *(const uint4*)(hb + ((unsigned int)sp[k] + moff));
        ACC8(v)
    }
    if (n > ELL_C) {
        int on = *ovf_n;
        if (on > OVF_CAP) on = OVF_CAP;
        for (int jj = 0; jj < on; ++jj) {
            int2 e = ovf[jj];
            if (e.x == d) {
                uint4 v = *(const uint4*)(hb + ((unsigned int)e.y + moff));
                ACC8(v)
            }
        }
    }
#undef ACC8

    float dd = rsqrtf((float)(n + 1));
    float4 bi0 = ((const float4*)bias)[2 * j], bi1 = ((const float4*)bias)[2 * j + 1];
    float4 g0  = ((const float4*)g)[2 * j],    g1  = ((const float4*)g)[2 * j + 1];
    float4 be0 = ((const float4*)be)[2 * j],   be1 = ((const float4*)be)[2 * j + 1];
    float4 mu0 = ((const float4*)mu)[2 * j],   mu1 = ((const float4*)mu)[2 * j + 1];
    float4 va0 = ((const float4*)var)[2 * j],  va1 = ((const float4*)var)[2 * j + 1];
    float l0 = asf(lv.x << 16), l1 = asf(lv.x & 0xffff0000u);
    float l2 = asf(lv.y << 16), l3 = asf(lv.y & 0xffff0000u);
    float l4 = asf(lv.z << 16), l5 = asf(lv.z & 0xffff0000u);
    float l6 = asf(lv.w << 16), l7 = asf(lv.w & 0xffff0000u);

#define EPI(A, BI, GV, BE, MU, VA, LO) \
    (fmaxf(((A) * dd + (BI) - (MU)) * ((GV) * rsqrtf((VA) + BN_EPS)) + (BE), 0.f) + (LO))
    float r0 = EPI(a[0], bi0.x, g0.x, be0.x, mu0.x, va0.x, l0);
    float r1 = EPI(a[1], bi0.y, g0.y, be0.y, mu0.y, va0.y, l1);
    float r2 = EPI(a[2], bi0.z, g0.z, be0.z, mu0.z, va0.z, l2);
    float r3 = EPI(a[3], bi0.w, g0.w, be0.w, mu0.w, va0.w, l3);
    float r4 = EPI(a[4], bi1.x, g1.x, be1.x, mu1.x, va1.x, l4);
    float r5 = EPI(a[5], bi1.y, g1.y, be1.y, mu1.y, va1.y, l5);
    float r6 = EPI(a[6], bi1.z, g1.z, be1.z, mu1.z, va1.z, l6);
    float r7 = EPI(a[7], bi1.w, g1.w, be1.w, mu1.w, va1.w, l7);
#undef EPI

    float4* op = (float4*)(out_f + (size_t)d * HID + j * 8);
    op[0] = make_float4(r0, r1, r2, r3);              // 32 B/lane, coalesced
    op[1] = make_float4(r4, r5, r6, r7);
}

extern "C" void kernel_launch(void* const* d_in, const int* in_sizes, int n_in,
                              void* d_out, int out_size, void* d_ws, size_t ws_size,
                              hipStream_t stream) {
    const float* x      = (const float*)d_in[0];
    const int*   eidx   = (const int*)d_in[1];
    const float* fc_w   = (const float*)d_in[2];
    const float* fc_b   = (const float*)d_in[3];
    const float* conv_w = (const float*)d_in[4];
    const float* conv_b = (const float*)d_in[5];
    const float* bn_g   = (const float*)d_in[6];
    const float* bn_b   = (const float*)d_in[7];
    const float* bn_m   = (const float*)d_in[8];
    const float* bn_v   = (const float*)d_in[9];

    const int* src = eidx;
    const int* dst = eidx + NEDGES;
    float* out = (float*)d_out;

    // workspace: slot | meta(ovf1_n, ovf2_n, pad, bin_n[256]) | ovf1 | ovf2 |
    //            ell | h0 | hws2 | hws | staged
    int*    slot    = (int*)d_ws;                     // written (not zeroed)
    int*    meta    = slot + NPAD;                    // 272 ints (memset'd)
    int*    ovf1_n  = meta;                           // meta[0]
    int*    ovf2_n  = meta + 1;                       // meta[1]
    int*    bin_n   = meta + 16;                      // meta[16..271]
    int2*   ovf1    = (int2*)(meta + 272);            // 8B-aligned
    int2*   ovf2    = ovf1 + OVF_CAP;
    int*    ell     = (int*)(ovf2 + OVF_CAP);         // N*32 ints = 12.8 MB
    ushort* h0      = (ushort*)(ell + (size_t)NNODES * ELL_C);  // N*64 bf16
    ushort* hws2    = h0 + (size_t)NNODES * HID;      // layer-2 gather source
    ushort* hws     = hws2 + (size_t)NNODES * HID;    // layer-1 gather source
    unsigned int* staged = (unsigned int*)(hws + (size_t)NNODES * HID);
                                                      // 256*10000*4 = 10.24 MB

    const int BLK = 256;

    // zero meta only (1 KB) -- slot is written non-atomically by fill_conv
    hipMemsetAsync(meta, 0, 272 * 4, stream);

    // K1: read-once radix binning co-runs with fc -> h0
    bin_fc<<<BIN_BLOCKS + MM_BLOCKS, BLK, 0, stream>>>(
        src, dst, staged, bin_n, ovf1_n, ovf1,
        x, fc_w, fc_b, bn_g, bn_b, bn_m, bn_v, h0);

    // K2: per-bin LDS-count fill + conv L1 fused (slot/ell final; hws out)
    fill_conv<<<BIN_N, 1024, 0, stream>>>(staged, bin_n, ovf1_n, ovf1,
                                          slot, ell, ovf2_n, ovf2,
                                          h0, conv_w, hws);

    // K3: gather L1 + conv L2 fused (hws -> hws2; h1 stays in LDS)
    gather_conv<<<GBLOCKS, BLK, 0, stream>>>(hws, slot, ell, ovf2_n, ovf2,
                                             conv_b, bn_g + HID, bn_b + HID,
                                             bn_m + HID, bn_v + HID, h0,
                                             conv_w + HID * HID, hws2);

    // K4: gather L2 -> out (f32)
    gather_update<<<GBLOCKS, BLK, 0, stream>>>(hws2, slot, ell, ovf2_n, ovf2,
                                               conv_b + HID, bn_g + 2 * HID, bn_b + 2 * HID,
                                               bn_m + 2 * HID, bn_v + 2 * HID,
                                               h0, out);
}